// Round 10
// baseline (138.819 us; speedup 1.0000x reference)
//
#include <hip/hip_runtime.h>

#define K_SEL 103
typedef unsigned long long ull_t;
typedef _Float16 f16x8 __attribute__((ext_vector_type(8)));
typedef short s16x8 __attribute__((ext_vector_type(8)));
typedef float f32x4 __attribute__((ext_vector_type(4)));

// ================= K12: fused (k2 select+MLP | k1 lin+W2th) =================
// grid 1024: blocks [0,512) = per-query select+MLP -> Hh (A-layout,
// unnormalized; invtot applied in k3), indg, invtot.
// blocks [512,1024) = xlh = fp16(x @ W_lin^T + b) (32 rows each) + W2th chunk.
__global__ __launch_bounds__(256, 4) void k12(const float* __restrict__ pos,
                                              const float* __restrict__ qpos,
                                              const float* __restrict__ Bmat,
                                              const float* __restrict__ W1,
                                              const float* __restrict__ b1,
                                              _Float16* __restrict__ Hh,
                                              int* __restrict__ indg,
                                              float* __restrict__ invtot,
                                              const float* __restrict__ x,
                                              const float* __restrict__ W,
                                              const float* __restrict__ b,
                                              _Float16* __restrict__ xlh,
                                              const float* __restrict__ W2,
                                              const float* __restrict__ filt,
                                              _Float16* __restrict__ W2th) {
    __shared__ __align__(16) unsigned char smem[30848];
    const int tid = threadIdx.x;
    const int bid = blockIdx.x;
    const int lane = tid & 63;
    const int wid = tid >> 6;

    if (bid >= 512) {
        // ---------------- k1 path: 32 rows + W2th chunk --------------------
        const int bb = bid - 512;
        float* Wt = (float*)smem;                  // 64x64 = 16 KB
        if (tid < 132) {
            int t = bb * 132 + tid;                // 512*132 = 67584 exactly
            int d = t & 31;
            int e = t >> 5;
            int c = e & 63;
            int j = e >> 6;
            float v = (j < 32) ? W2[(c * 32 + d) * 32 + j] : filt[c * 32 + d];
            W2th[d * 2112 + e] = (_Float16)v;
        }
        for (int t = tid; t < 4096; t += 256)
            Wt[(t & 63) * 64 + (t >> 6)] = W[t];
        __syncthreads();
        const int i = tid & 63;
        const int sub = tid >> 6;
        const float bi = b[i];
        #pragma unroll
        for (int rr = 0; rr < 2; ++rr) {
            const int r0 = bb * 32 + rr * 16 + sub * 4;
            float acc0 = bi, acc1 = bi, acc2 = bi, acc3 = bi;
            const float* xr = x + (size_t)r0 * 64;
            #pragma unroll 4
            for (int jj = 0; jj < 16; ++jj) {
                float4 v0 = *(const float4*)(xr + 0 * 64 + jj * 4);
                float4 v1 = *(const float4*)(xr + 1 * 64 + jj * 4);
                float4 v2 = *(const float4*)(xr + 2 * 64 + jj * 4);
                float4 v3 = *(const float4*)(xr + 3 * 64 + jj * 4);
                float w0 = Wt[(jj * 4 + 0) * 64 + i];
                float w1 = Wt[(jj * 4 + 1) * 64 + i];
                float w2 = Wt[(jj * 4 + 2) * 64 + i];
                float w3 = Wt[(jj * 4 + 3) * 64 + i];
                acc0 += v0.x * w0 + v0.y * w1 + v0.z * w2 + v0.w * w3;
                acc1 += v1.x * w0 + v1.y * w1 + v1.z * w2 + v1.w * w3;
                acc2 += v2.x * w0 + v2.y * w1 + v2.z * w2 + v2.w * w3;
                acc3 += v3.x * w0 + v3.y * w1 + v3.z * w2 + v3.w * w3;
            }
            xlh[(size_t)(r0 + 0) * 64 + i] = (_Float16)acc0;
            xlh[(size_t)(r0 + 1) * 64 + i] = (_Float16)acc1;
            xlh[(size_t)(r0 + 2) * 64 + i] = (_Float16)acc2;
            xlh[(size_t)(r0 + 3) * 64 + i] = (_Float16)acc3;
        }
        return;
    }

    // ---------------- k2 path: select + MLP --------------------------------
    const int q = bid;
    unsigned* ebits   = (unsigned*)(smem);            // 8192 B
    unsigned* hist    = (unsigned*)(smem + 8192);     // 16384 B
    _Float16* Hs      = (_Float16*)(smem + 8192);     // 12288 B (alias hist)
    float*    W1s     = (float*)(smem + 24576);       // 4096 B
    float*    b1s     = (float*)(smem + 28672);
    float*    Bm      = (float*)(smem + 28800);
    int*      sel_v   = (int*)(smem + 28928);         // 104
    float*    sel_e   = (float*)(smem + 29344);       // 104
    ull_t*    bnd     = (ull_t*)(smem + 29760);       // 128
    int*      counters= (int*)(smem + 30784);
    int*      info    = (int*)(smem + 30792);
    float*    wred    = (float*)(smem + 30800);       // 4
    float*    emax_s  = (float*)(smem + 30816);
    unsigned* wscan   = (unsigned*)(smem + 30824);    // 4

    for (int t = tid; t < 1024; t += 256) W1s[t] = W1[t];
    if (tid < 32) { b1s[tid] = b1[tid]; Bm[tid] = Bmat[tid]; }
    if (tid < 2)  counters[tid] = 0;
    for (int t = tid; t < 1024; t += 256) ((uint4*)hist)[t] = make_uint4(0, 0, 0, 0);
    const float qp0 = qpos[q * 2 + 0];
    const float qp1 = qpos[q * 2 + 1];
    __syncthreads();

    float lmin = 1e30f;
    for (int v = tid; v < 2048; v += 256) {
        float2 p = ((const float2*)pos)[v];
        float d0 = qp0 - p.x;
        float d1 = qp1 - p.y;
        d0 += 0.5f; d0 -= floorf(d0); d0 -= 0.5f;
        d1 += 0.5f; d1 -= floorf(d1); d1 -= 0.5f;
        float e = d0 * d0 + d1 * d1;
        ebits[v] = __float_as_uint(e);
        lmin = fminf(lmin, e);
        int bb2 = (int)(e * 8192.0f); bb2 = (bb2 > 4095) ? 4095 : bb2;
        atomicAdd(&hist[bb2], 1u);
    }
    #pragma unroll
    for (int off = 32; off > 0; off >>= 1)
        lmin = fminf(lmin, __shfl_xor(lmin, off, 64));
    if (lane == 0) wred[wid] = lmin;
    __syncthreads();
    const float e_min = fminf(fminf(wred[0], wred[1]), fminf(wred[2], wred[3]));

    unsigned lsum = 0;
    #pragma unroll
    for (int i = 0; i < 16; ++i) lsum += hist[tid * 16 + i];
    unsigned vq = lsum;
    #pragma unroll
    for (int off = 1; off < 64; off <<= 1) {
        unsigned n = __shfl_up(vq, off, 64);
        if (lane >= off) vq += n;
    }
    if (lane == 63) wscan[wid] = vq;
    __syncthreads();
    unsigned base = 0;
    for (int w2 = 0; w2 < wid; ++w2) base += wscan[w2];
    unsigned cum = base + vq - lsum;
    #pragma unroll
    for (int i = 0; i < 16; ++i) {
        unsigned cnt = hist[tid * 16 + i];
        if (cum <= 102u && 102u < cum + cnt) { info[0] = tid * 16 + i; info[1] = (int)cum; }
        cum += cnt;
    }
    __syncthreads();          // all hist reads done -> hist dead
    const int Bstar = info[0];
    const int L = info[1];
    const int need = K_SEL - L;

    // compaction + zero Hs (aliases dead hist; sel/bnd live outside)
    {
        f16x8 z = {0, 0, 0, 0, 0, 0, 0, 0};
        for (int t = tid; t < 768; t += 256) ((f16x8*)Hs)[t] = z;
    }
    for (int v = tid; v < 2048; v += 256) {
        unsigned bb2 = ebits[v];
        float e = __uint_as_float(bb2);
        int bin = (int)(e * 8192.0f); bin = (bin > 4095) ? 4095 : bin;
        if (bin < Bstar) {
            int s2 = atomicAdd(&counters[0], 1);
            sel_v[s2] = v; sel_e[s2] = e;
        } else if (bin == Bstar) {
            int s2 = atomicAdd(&counters[1], 1);
            if (s2 < 128) bnd[s2] = (((ull_t)bb2) << 32) | (unsigned)v;
        }
    }
    __syncthreads();
    if (tid == 0) {
        int nb = counters[1]; if (nb > 128) nb = 128;
        for (int i = 1; i < nb; ++i) {
            ull_t key = bnd[i]; int j2 = i - 1;
            while (j2 >= 0 && bnd[j2] > key) { bnd[j2 + 1] = bnd[j2]; --j2; }
            bnd[j2 + 1] = key;
        }
        for (int i = 0; i < need; ++i) {
            sel_v[L + i] = (int)(unsigned)(bnd[i] & 0xffffffffull);
            sel_e[L + i] = __uint_as_float((unsigned)(bnd[i] >> 32));
        }
        emax_s[0] = __uint_as_float((unsigned)(bnd[need - 1] >> 32));
    }
    __syncthreads();

    const float denom = (emax_s[0] - e_min) + 1e-8f;
    float w = 0.0f;
    if (tid < K_SEL) {
        w = __expf(-(sel_e[tid] - e_min) / denom);
        sel_e[tid] = w;
    }
    float sw = w;
    #pragma unroll
    for (int off = 32; off > 0; off >>= 1)
        sw += __shfl_xor(sw, off, 64);
    if (lane == 0) wred[wid] = sw;
    __syncthreads();
    if (tid == 0)
        invtot[q] = 1.0f / (wred[0] + wred[1] + wred[2] + wred[3]);

    // MLP with unnormalized w: 2 threads per k
    if (tid < 2 * K_SEL) {
        const int k = tid >> 1;
        const int io = (tid & 1) * 16;
        const int v = sel_v[k];
        const float wk = sel_e[k];
        float2 p = ((const float2*)pos)[v];
        float d0 = qp0 - p.x;
        float d1 = qp1 - p.y;
        d0 += 0.5f; d0 -= floorf(d0); d0 -= 0.5f;
        d1 += 0.5f; d1 -= floorf(d1); d1 -= 0.5f;
        float kf[32];
        #pragma unroll
        for (int f = 0; f < 16; ++f) {
            float t = d0 * Bm[f] + d1 * Bm[16 + f];   // revolutions
            float r = t - rintf(t);
            kf[f]      = __builtin_amdgcn_sinf(r);
            kf[16 + f] = __builtin_amdgcn_cosf(r);
        }
        #pragma unroll 4
        for (int i = io; i < io + 16; ++i) {
            float pre = b1s[i];
            #pragma unroll
            for (int jf = 0; jf < 32; ++jf) pre += kf[jf] * W1s[i * 32 + jf];
            float g = 0.5f * pre * (1.0f + erff(pre * 0.70710678118654752f));
            Hs[i * 128 + k] = (_Float16)(g * wk);
        }
        if (io == 0) {
            Hs[32 * 128 + k] = (_Float16)wk;
            indg[q * K_SEL + k] = v;
        }
    }
    __syncthreads();
    {
        _Float16* hq = Hh + (size_t)q * 6144;
        for (int t = tid; t < 768; t += 256)
            ((f16x8*)hq)[t] = ((const f16x8*)Hs)[t];
    }
}

// ---------------- K3: MFMA GEMM1+GEMM2, block = (q, bt-pair), 1-bt passes ---
// grid 2048. LDS ~26 KB -> 5-6 blocks/CU. Xg single-bt swizzled
// (element (c,k) at c*136 + 8*(c>>3) + k halfs); Zh[2][2112] separate so
// pass-B gather overlaps; red aliases dead Xg. Transpose writes are b32
// k-pairs (32 stores/pass, ~2-way banks). Both passes' gathers issued up
// front (8 f16x8 in flight).
__global__ __launch_bounds__(256, 5) void k3_main(const _Float16* __restrict__ xlh,
                                                  const _Float16* __restrict__ Hh,
                                                  const int* __restrict__ indg,
                                                  const _Float16* __restrict__ W2th,
                                                  const float* __restrict__ bias,
                                                  const float* __restrict__ invtot,
                                                  float* __restrict__ out) {
    const int bid = blockIdx.x;
    const int q = bid >> 2;
    const int pr = bid & 3;            // bt pair: {2pr, 2pr+1}
    const int tid = threadIdx.x;
    const int lane = tid & 63;
    const int wv = tid >> 6;
    const int n0 = lane & 15;
    const int quad = lane >> 4;

    __shared__ __align__(16) unsigned char smem[26464];
    _Float16* Xg   = (_Float16*)smem;                // 8752 halfs = 17504 B
    _Float16* Zh   = (_Float16*)(smem + 17504);      // 2*2112 halfs = 8448 B
    int*      ind_s= (int*)(smem + 25952);           // 128 ints
    float*    red  = (float*)smem;                   // aliases dead Xg (end)

    // ---- setup
    const _Float16* hq = Hh + (size_t)q * 6144;
    f16x8 afr[4][3];
    #pragma unroll
    for (int ks = 0; ks < 4; ++ks)
        #pragma unroll
        for (int r = 0; r < 3; ++r)
            afr[ks][r] = *(const f16x8*)(hq + (r * 16 + n0) * 128 + ks * 32 + quad * 8);
    const float it = invtot[q];
    if (tid < 128) {
        int kk = (tid < K_SEL) ? tid : tid - K_SEL;
        ind_s[tid] = indg[q * K_SEL + kk];
    }
    __syncthreads();                                             // B0

    // gather slot decomposition: slot s = tid + i*256, i in {0,1}
    int g_k2[2], g_oct[2];
    #pragma unroll
    for (int i = 0; i < 2; ++i) {
        int s = tid + i * 256;
        g_k2[i] = s >> 3;          // k-pair index [0,64)
        g_oct[i] = s & 7;
    }
    const int btA = pr * 2, btB = pr * 2 + 1;

    // ---- issue ALL gather loads (both passes) up front
    f16x8 vA[2][2], vB[2][2];
    #pragma unroll
    for (int i = 0; i < 2; ++i) {
        const int ka = ind_s[2 * g_k2[i]];
        const int kb = ind_s[2 * g_k2[i] + 1];
        vA[i][0] = *(const f16x8*)(xlh + ((size_t)btA * 2048 + ka) * 64 + g_oct[i] * 8);
        vA[i][1] = *(const f16x8*)(xlh + ((size_t)btA * 2048 + kb) * 64 + g_oct[i] * 8);
        vB[i][0] = *(const f16x8*)(xlh + ((size_t)btB * 2048 + ka) * 64 + g_oct[i] * 8);
        vB[i][1] = *(const f16x8*)(xlh + ((size_t)btB * 2048 + kb) * 64 + g_oct[i] * 8);
    }

    // ---- pass A transpose-write (b32 k-pairs)
    #pragma unroll
    for (int i = 0; i < 2; ++i) {
        s16x8 lo = __builtin_bit_cast(s16x8, vA[i][0]);
        s16x8 hi = __builtin_bit_cast(s16x8, vA[i][1]);
        int base = g_oct[i] * 1096 + 2 * g_k2[i];    // oct*(8*136+8) + 2k2
        #pragma unroll
        for (int cc = 0; cc < 8; ++cc) {
            unsigned u = ((unsigned)(unsigned short)lo[cc]) |
                         (((unsigned)(unsigned short)hi[cc]) << 16);
            *(unsigned*)(&Xg[base + 136 * cc]) = u;
        }
    }
    __syncthreads();                                             // B1

    // ---- GEMM1 pass A (wave wv covers c-tile wv)
    f32x4 DzA[3];
    #pragma unroll
    for (int r = 0; r < 3; ++r) DzA[r] = (f32x4){0.f, 0.f, 0.f, 0.f};
    const int cA = wv * 16 + n0;
    const int cswz = cA * 136 + ((cA >> 3) << 3);
    #pragma unroll
    for (int ks = 0; ks < 4; ++ks) {
        f16x8 bfr = *(const f16x8*)(&Xg[cswz + ks * 32 + quad * 8]);
        #pragma unroll
        for (int r = 0; r < 3; ++r)
            DzA[r] = __builtin_amdgcn_mfma_f32_16x16x32_f16(afr[ks][r], bfr, DzA[r], 0, 0, 0);
    }
    __syncthreads();                                             // B2 (Xg dead)

    // ---- pass B transpose-write + Zh pass A write (disjoint regions)
    #pragma unroll
    for (int i = 0; i < 2; ++i) {
        s16x8 lo = __builtin_bit_cast(s16x8, vB[i][0]);
        s16x8 hi = __builtin_bit_cast(s16x8, vB[i][1]);
        int base = g_oct[i] * 1096 + 2 * g_k2[i];
        #pragma unroll
        for (int cc = 0; cc < 8; ++cc) {
            unsigned u = ((unsigned)(unsigned short)lo[cc]) |
                         (((unsigned)(unsigned short)hi[cc]) << 16);
            *(unsigned*)(&Xg[base + 136 * cc]) = u;
        }
    }
    #pragma unroll
    for (int r = 0; r < 3; ++r)
        #pragma unroll
        for (int reg = 0; reg < 4; ++reg) {
            int j = r * 16 + quad * 4 + reg;
            if (j < 33) Zh[j * 64 + cA] = (_Float16)DzA[r][reg];
        }
    __syncthreads();                                             // B3

    // ---- GEMM1 pass B
    f32x4 DzB[3];
    #pragma unroll
    for (int r = 0; r < 3; ++r) DzB[r] = (f32x4){0.f, 0.f, 0.f, 0.f};
    #pragma unroll
    for (int ks = 0; ks < 4; ++ks) {
        f16x8 bfr = *(const f16x8*)(&Xg[cswz + ks * 32 + quad * 8]);
        #pragma unroll
        for (int r = 0; r < 3; ++r)
            DzB[r] = __builtin_amdgcn_mfma_f32_16x16x32_f16(afr[ks][r], bfr, DzB[r], 0, 0, 0);
    }
    #pragma unroll
    for (int r = 0; r < 3; ++r)
        #pragma unroll
        for (int reg = 0; reg < 4; ++reg) {
            int j = r * 16 + quad * 4 + reg;
            if (j < 33) Zh[2112 + j * 64 + cA] = (_Float16)DzB[r][reg];
        }
    __syncthreads();                                             // B4

    // ---- GEMM2 (M=2): dual accumulator chains over s = wv, wv+4, ...
    f32x4 D2[2][2];
    #pragma unroll
    for (int p = 0; p < 2; ++p)
        #pragma unroll
        for (int dt = 0; dt < 2; ++dt) D2[p][dt] = (f32x4){0.f, 0.f, 0.f, 0.f};
    int p = 0;
    #pragma unroll 2
    for (int s = wv; s < 66; s += 4) {
        const int e0 = s * 32 + quad * 8;
        f16x8 afr2 = {0, 0, 0, 0, 0, 0, 0, 0};
        if (n0 < 2) afr2 = *(const f16x8*)(&Zh[n0 * 2112 + e0]);
        #pragma unroll
        for (int dt = 0; dt < 2; ++dt) {
            f16x8 bfr = *(const f16x8*)(W2th + (size_t)(dt * 16 + n0) * 2112 + e0);
            D2[p][dt] = __builtin_amdgcn_mfma_f32_16x16x32_f16(afr2, bfr, D2[p][dt], 0, 0, 0);
        }
        p ^= 1;
    }
    #pragma unroll
    for (int dt = 0; dt < 2; ++dt)
        D2[0][dt] = D2[0][dt] + D2[1][dt];
    __syncthreads();                                             // B5 (Xg dead -> red)

    if (quad == 0) {
        red[(wv * 4 + 0) * 16 + n0] = D2[0][0][0];   // dt0 btl0
        red[(wv * 4 + 1) * 16 + n0] = D2[0][0][1];   // dt0 btl1
        red[(wv * 4 + 2) * 16 + n0] = D2[0][1][0];   // dt1 btl0
        red[(wv * 4 + 3) * 16 + n0] = D2[0][1][1];   // dt1 btl1
    }
    __syncthreads();                                             // B6
    if (tid < 64) {
        const int btl = tid >> 5;
        const int d = tid & 31;
        const int dt = d >> 4;
        const int dn = d & 15;
        float s = 0.0f;
        #pragma unroll
        for (int w2 = 0; w2 < 4; ++w2)
            s += red[(w2 * 4 + dt * 2 + btl) * 16 + dn];
        out[((size_t)(pr * 2 + btl) * 512 + q) * 32 + d] = bias[d] + it * s;
    }
}

// ---------------------------------------------------------------------------
extern "C" void kernel_launch(void* const* d_in, const int* in_sizes, int n_in,
                              void* d_out, int out_size, void* d_ws, size_t ws_size,
                              hipStream_t stream) {
    const float* x     = (const float*)d_in[0];   // (2,4,2048,64)
    const float* pos   = (const float*)d_in[1];   // (2048,2)
    const float* qpos  = (const float*)d_in[2];   // (512,2)
    const float* W_lin = (const float*)d_in[3];   // (64,64)
    const float* b_lin = (const float*)d_in[4];   // (64)
    const float* Bmat  = (const float*)d_in[5];   // (2,16)
    const float* W1    = (const float*)d_in[6];   // (32,32)
    const float* b1    = (const float*)d_in[7];   // (32)
    const float* W2    = (const float*)d_in[8];   // (2048,32)
    const float* filt  = (const float*)d_in[9];   // (2048)
    const float* bias  = (const float*)d_in[10];  // (32)
    float* out = (float*)d_out;

    float* ws = (float*)d_ws;
    _Float16* xlh    = (_Float16*)ws;               // 1048576 halfs
    _Float16* Hh     = (_Float16*)(ws + 524288);    // 512*6144 halfs
    int*      indg   = (int*)(ws + 2097152);        // 52736 ints
    _Float16* W2th   = (_Float16*)(ws + 2150144);   // 32*2112 halfs
    float*    invtot = ws + 2183936;                // 512 floats

    k12<<<1024, 256, 0, stream>>>(pos, qpos, Bmat, W1, b1, Hh, indg, invtot,
                                  x, W_lin, b_lin, xlh, W2, filt, W2th);
    k3_main<<<2048, 256, 0, stream>>>(xlh, Hh, indg, W2th, bias, invtot, out);
}